// Round 1
// 1734.673 us; speedup vs baseline: 1.0755x; 1.0755x over previous
//
#include <hip/hip_runtime.h>

constexpr int N_NODES = 16384;
constexpr int DIN     = 512;
constexpr int DCAT    = 1024;   // HEADS*D_HEAD = 2*512
constexpr int NE      = 524288;
constexpr int ET      = NE + N_NODES;   // edges + self loops

// ---------------------------------------------------------------------------
// Detect whether edge_index buffer is int64 (high words all zero) or int32.
// flag stays 0 -> int64 layout; nonzero -> int32 layout.
__global__ __launch_bounds__(256) void detect_kernel(const int* __restrict__ ei,
                                                     int* __restrict__ flag) {
  int nz = 0;
  for (int i = threadIdx.x; i < 4096; i += 256) nz |= ei[2 * i + 1];
  if (nz) atomicOr(flag, 1);
}

__global__ __launch_bounds__(256) void count_kernel(const int* __restrict__ ei,
                                                    const int* __restrict__ flag,
                                                    int* __restrict__ cnt) {
  int e = blockIdx.x * 256 + threadIdx.x;
  if (e >= ET) return;
  int is64 = (*flag == 0);
  int dst;
  if (e < NE) {
    int di = NE + e;
    dst = ei[is64 ? 2 * di : di];
  } else {
    dst = e - NE;
  }
  atomicAdd(&cnt[dst], 1);
}

__global__ __launch_bounds__(1024) void scan_kernel(const int* __restrict__ cnt,
                                                    int* __restrict__ rowptr) {
  __shared__ int sums[1024];
  int tid = threadIdx.x;
  int local[16];
  int s = 0;
#pragma unroll
  for (int i = 0; i < 16; ++i) { local[i] = s; s += cnt[tid * 16 + i]; }
  sums[tid] = s;
  __syncthreads();
  for (int off = 1; off < 1024; off <<= 1) {
    int v = 0;
    if (tid >= off) v = sums[tid - off];
    __syncthreads();
    sums[tid] += v;
    __syncthreads();
  }
  int base = (tid == 0) ? 0 : sums[tid - 1];
#pragma unroll
  for (int i = 0; i < 16; ++i) rowptr[tid * 16 + i] = base + local[i];
  if (tid == 1023) rowptr[N_NODES] = sums[1023];
}

__global__ __launch_bounds__(256) void scatter_kernel(const int* __restrict__ ei,
                                                      const int* __restrict__ flag,
                                                      const int* __restrict__ rowptr,
                                                      int* __restrict__ cursor,
                                                      int* __restrict__ esrc) {
  int e = blockIdx.x * 256 + threadIdx.x;
  if (e >= ET) return;
  int is64 = (*flag == 0);
  int src, dst;
  if (e < NE) {
    src = ei[is64 ? 2 * e : e];
    int di = NE + e;
    dst = ei[is64 ? 2 * di : di];
  } else {
    src = dst = e - NE;
  }
  int pos = atomicAdd(&cursor[dst], 1);
  esrc[rowptr[dst] + pos] = src;
}

// ---------------------------------------------------------------------------
// GEMM1: xh = x @ W.  A [16384,512] * B [512,1024] -> C [16384,1024], fp32.
// 128x128 tile, 256 threads, 8x8 microtile.
__global__ __launch_bounds__(256) void gemm1_kernel(const float* __restrict__ A,
                                                    const float* __restrict__ B,
                                                    float* __restrict__ C) {
  constexpr int BM = 128, BN = 128, BK = 8;
  __shared__ float As[BK][BM];   // transposed A tile
  __shared__ float Bs[BK][BN];
  int tid = threadIdx.x;
  int bm = blockIdx.y * BM;
  int bn = blockIdx.x * BN;
  int arow = tid >> 1, akq = (tid & 1) * 4;      // A: 128 rows x 8 k, float4 along k
  int brow = tid >> 5, bcol = (tid & 31) * 4;    // B: 8 k x 128 cols, float4 along n
  int tm = (tid >> 4) * 8;
  int tn = (tid & 15) * 8;
  float acc[8][8];
#pragma unroll
  for (int i = 0; i < 8; ++i)
#pragma unroll
    for (int j = 0; j < 8; ++j) acc[i][j] = 0.f;

  for (int k0 = 0; k0 < DIN; k0 += BK) {
    float4 a4 = *(const float4*)(A + (size_t)(bm + arow) * DIN + k0 + akq);
    As[akq + 0][arow] = a4.x;
    As[akq + 1][arow] = a4.y;
    As[akq + 2][arow] = a4.z;
    As[akq + 3][arow] = a4.w;
    *(float4*)(&Bs[brow][bcol]) =
        *(const float4*)(B + (size_t)(k0 + brow) * DCAT + bn + bcol);
    __syncthreads();
#pragma unroll
    for (int kk = 0; kk < BK; ++kk) {
      float a[8], b[8];
#pragma unroll
      for (int i = 0; i < 8; ++i) a[i] = As[kk][tm + i];
#pragma unroll
      for (int j = 0; j < 8; ++j) b[j] = Bs[kk][tn + j];
#pragma unroll
      for (int i = 0; i < 8; ++i)
#pragma unroll
        for (int j = 0; j < 8; ++j) acc[i][j] += a[i] * b[j];
    }
    __syncthreads();
  }
#pragma unroll
  for (int i = 0; i < 8; ++i)
#pragma unroll
    for (int j = 0; j < 8; j += 4) {
      float4 v = make_float4(acc[i][j], acc[i][j + 1], acc[i][j + 2], acc[i][j + 3]);
      *(float4*)(C + (size_t)(bm + tm + i) * DCAT + bn + tn + j) = v;
    }
}

// ---------------------------------------------------------------------------
// a_src[n,h] = sum_c xh[n,h,c]*att_src[h,c]; same for a_dst. One wave per (n,h).
__global__ __launch_bounds__(256) void avec_kernel(const float* __restrict__ xh,
                                                   const float* __restrict__ att_src,
                                                   const float* __restrict__ att_dst,
                                                   float* __restrict__ asrc,
                                                   float* __restrict__ adst) {
  int w = blockIdx.x * 4 + (threadIdx.x >> 6);
  int lane = threadIdx.x & 63;
  int n = w >> 1, h = w & 1;
  const float* row = xh + (size_t)n * DCAT + h * 512;
  const float* as = att_src + h * 512;
  const float* ad = att_dst + h * 512;
  float s1 = 0.f, s2 = 0.f;
  for (int c = lane; c < 512; c += 64) {
    float v = row[c];
    s1 += v * as[c];
    s2 += v * ad[c];
  }
  for (int off = 32; off > 0; off >>= 1) {
    s1 += __shfl_down(s1, off);
    s2 += __shfl_down(s2, off);
  }
  if (lane == 0) {
    asrc[n * 2 + h] = s1;
    adst[n * 2 + h] = s2;
  }
}

// ---------------------------------------------------------------------------
// Per-dst-node: softmax over incoming edges (2 heads) + weighted aggregation of
// xh[src], then +bias and ReLU.  One block (256 thr) per node; thread t owns
// channels [4t, 4t+4).
__global__ __launch_bounds__(256) void agg_kernel(const float* __restrict__ xh,
                                                  const float* __restrict__ asrc,
                                                  const float* __restrict__ adst,
                                                  const int* __restrict__ rowptr,
                                                  const int* __restrict__ esrc,
                                                  const float* __restrict__ bias,
                                                  float* __restrict__ hagg) {
  __shared__ float4 red[256];       // (m0,z0,m1,z1) per thread
  __shared__ int   sbuf[256];
  __shared__ float w0buf[256];
  __shared__ float w1buf[256];

  int dst = blockIdx.x;
  int tid = threadIdx.x;
  int start = rowptr[dst];
  int deg = rowptr[dst + 1] - start;
  float ad0 = adst[2 * dst], ad1 = adst[2 * dst + 1];

  // phase 1: per-thread online (m,z), then block merge
  float m0 = -1e30f, z0 = 0.f, m1 = -1e30f, z1 = 0.f;
  for (int i = tid; i < deg; i += 256) {
    int s = esrc[start + i];
    float l0 = asrc[2 * s] + ad0;     l0 = l0 > 0.f ? l0 : 0.2f * l0;
    float l1 = asrc[2 * s + 1] + ad1; l1 = l1 > 0.f ? l1 : 0.2f * l1;
    if (l0 > m0) { z0 = z0 * __expf(m0 - l0) + 1.f; m0 = l0; } else { z0 += __expf(l0 - m0); }
    if (l1 > m1) { z1 = z1 * __expf(m1 - l1) + 1.f; m1 = l1; } else { z1 += __expf(l1 - m1); }
  }
  red[tid] = make_float4(m0, z0, m1, z1);
  __syncthreads();
  for (int s = 128; s > 0; s >>= 1) {
    if (tid < s) {
      float4 a = red[tid], b = red[tid + s];
      float M0 = fmaxf(a.x, b.x);
      float Z0 = a.y * __expf(a.x - M0) + b.y * __expf(b.x - M0);
      float M1 = fmaxf(a.z, b.z);
      float Z1 = a.w * __expf(a.z - M1) + b.w * __expf(b.z - M1);
      red[tid] = make_float4(M0, Z0, M1, Z1);
    }
    __syncthreads();
  }
  float4 fin = red[0];
  float fm0 = fin.x, fm1 = fin.z;
  float rz0 = 1.f / fmaxf(fin.y, 1e-16f);
  float rz1 = 1.f / fmaxf(fin.w, 1e-16f);

  // phase 2: chunked alpha computation + gather-accumulate (4x unrolled so 4
  // independent float4 gathers are in flight per iteration)
  int c0 = tid * 4;                  // channel base, 0..1020
  bool head1 = (c0 >= 512);
  float4 acc = make_float4(0.f, 0.f, 0.f, 0.f);
  for (int ch = 0; ch < deg; ch += 256) {
    int cnt = min(256, deg - ch);
    __syncthreads();
    if (tid < cnt) {
      int s = esrc[start + ch + tid];
      sbuf[tid] = s;
      float l0 = asrc[2 * s] + ad0;     l0 = l0 > 0.f ? l0 : 0.2f * l0;
      float l1 = asrc[2 * s + 1] + ad1; l1 = l1 > 0.f ? l1 : 0.2f * l1;
      w0buf[tid] = __expf(l0 - fm0);
      w1buf[tid] = __expf(l1 - fm1);
    }
    __syncthreads();
    const float* wbuf = head1 ? w1buf : w0buf;
    int j = 0;
    for (; j + 4 <= cnt; j += 4) {
      int s0 = sbuf[j + 0], s1 = sbuf[j + 1], s2 = sbuf[j + 2], s3 = sbuf[j + 3];
      float fw0 = wbuf[j + 0], fw1 = wbuf[j + 1], fw2 = wbuf[j + 2], fw3 = wbuf[j + 3];
      float4 v0 = *(const float4*)(xh + (size_t)s0 * DCAT + c0);
      float4 v1 = *(const float4*)(xh + (size_t)s1 * DCAT + c0);
      float4 v2 = *(const float4*)(xh + (size_t)s2 * DCAT + c0);
      float4 v3 = *(const float4*)(xh + (size_t)s3 * DCAT + c0);
      acc.x += fw0 * v0.x; acc.y += fw0 * v0.y; acc.z += fw0 * v0.z; acc.w += fw0 * v0.w;
      acc.x += fw1 * v1.x; acc.y += fw1 * v1.y; acc.z += fw1 * v1.z; acc.w += fw1 * v1.w;
      acc.x += fw2 * v2.x; acc.y += fw2 * v2.y; acc.z += fw2 * v2.z; acc.w += fw2 * v2.w;
      acc.x += fw3 * v3.x; acc.y += fw3 * v3.y; acc.z += fw3 * v3.z; acc.w += fw3 * v3.w;
    }
    for (; j < cnt; ++j) {
      float w = wbuf[j];
      const float4 v = *(const float4*)(xh + (size_t)sbuf[j] * DCAT + c0);
      acc.x += w * v.x;
      acc.y += w * v.y;
      acc.z += w * v.z;
      acc.w += w * v.w;
    }
  }
  float rz = head1 ? rz1 : rz0;
  float4 b4 = *(const float4*)(bias + c0);
  float4 o;
  o.x = fmaxf(acc.x * rz + b4.x, 0.f);
  o.y = fmaxf(acc.y * rz + b4.y, 0.f);
  o.z = fmaxf(acc.z * rz + b4.z, 0.f);
  o.w = fmaxf(acc.w * rz + b4.w, 0.f);
  *(float4*)(hagg + (size_t)dst * DCAT + c0) = o;
}

// ---------------------------------------------------------------------------
// MLP layer A as a proper tiled GEMM: h1 = relu(hagg[16384,1024] @ Wa[1024,128] + ba).
// 32x128 tile per block (512 blocks), 256 threads, 4x4 microtile, BK=16.
__global__ __launch_bounds__(256) void mlpA_kernel(const float* __restrict__ hagg,
                                                   const float* __restrict__ Wa,
                                                   const float* __restrict__ ba,
                                                   float* __restrict__ h1) {
  constexpr int BM = 32, BK = 16;
  __shared__ float Ast[BK][BM];    // [k][m] transposed A tile
  __shared__ float Bs[BK][128];
  int tid = threadIdx.x;
  int bm = blockIdx.x * BM;
  int rowg = tid >> 5;             // 0..7
  int colg = tid & 31;             // 0..31
  int tm = rowg * 4, tn = colg * 4;
  float acc[4][4];
#pragma unroll
  for (int i = 0; i < 4; ++i)
#pragma unroll
    for (int j = 0; j < 4; ++j) acc[i][j] = 0.f;

  int ar = tid >> 2;               // 0..31 (for tid<128)
  int akq = (tid & 3) * 4;
  for (int k0 = 0; k0 < DCAT; k0 += BK) {
    if (tid < 128) {
      float4 v = *(const float4*)(hagg + (size_t)(bm + ar) * DCAT + k0 + akq);
      Ast[akq + 0][ar] = v.x;
      Ast[akq + 1][ar] = v.y;
      Ast[akq + 2][ar] = v.z;
      Ast[akq + 3][ar] = v.w;
    }
    {
      int r0 = tid >> 5, c0q = (tid & 31) * 4;           // rows 0..7
      *(float4*)&Bs[r0][c0q] = *(const float4*)(Wa + (size_t)(k0 + r0) * 128 + c0q);
      int r1 = r0 + 8;                                    // rows 8..15
      *(float4*)&Bs[r1][c0q] = *(const float4*)(Wa + (size_t)(k0 + r1) * 128 + c0q);
    }
    __syncthreads();
#pragma unroll
    for (int kk = 0; kk < BK; ++kk) {
      float4 a4 = *(const float4*)&Ast[kk][tm];
      float4 b4 = *(const float4*)&Bs[kk][tn];
      float av[4] = {a4.x, a4.y, a4.z, a4.w};
      float bv[4] = {b4.x, b4.y, b4.z, b4.w};
#pragma unroll
      for (int i = 0; i < 4; ++i)
#pragma unroll
        for (int j = 0; j < 4; ++j) acc[i][j] += av[i] * bv[j];
    }
    __syncthreads();
  }
  float4 bb = *(const float4*)(ba + tn);
  float bbv[4] = {bb.x, bb.y, bb.z, bb.w};
#pragma unroll
  for (int i = 0; i < 4; ++i) {
    float4 o;
    o.x = fmaxf(acc[i][0] + bbv[0], 0.f);
    o.y = fmaxf(acc[i][1] + bbv[1], 0.f);
    o.z = fmaxf(acc[i][2] + bbv[2], 0.f);
    o.w = fmaxf(acc[i][3] + bbv[3], 0.f);
    *(float4*)(h1 + (size_t)(bm + tm + i) * 128 + tn) = o;
  }
}

// ---------------------------------------------------------------------------
// MLP layers B+C fused: h3 = relu(h1 @ W1 + b1) @ W2 + b2.
// 64 nodes per block (256 blocks), 256 threads.  All operands staged in padded LDS.
__global__ __launch_bounds__(256) void mlpBC_kernel(const float* __restrict__ h1g,
                                                    const float* __restrict__ W1,
                                                    const float* __restrict__ b1,
                                                    const float* __restrict__ W2,
                                                    const float* __restrict__ b2,
                                                    float* __restrict__ h3) {
  __shared__ float sh1[64][132];   // 64 x 128, padded
  __shared__ float sW1[128][68];   // 128 x 64, padded
  __shared__ float sh2[64][68];    // 64 x 64, padded
  __shared__ float sW2[192];       // 64 x 3
  int tid = threadIdx.x;
  int n0 = blockIdx.x * 64;

#pragma unroll
  for (int q = 0; q < 8; ++q) {
    int s = tid + q * 256;
    int r = s >> 5, cq = (s & 31) * 4;
    *(float4*)&sh1[r][cq] = *(const float4*)(h1g + (size_t)(n0 + r) * 128 + cq);
  }
#pragma unroll
  for (int q = 0; q < 8; ++q) {
    int s = tid + q * 256;
    int r = s >> 4, cq = (s & 15) * 4;
    *(float4*)&sW1[r][cq] = *(const float4*)(W1 + (size_t)r * 64 + cq);
  }
  if (tid < 192) sW2[tid] = W2[tid];
  __syncthreads();

  // layer B: thread owns 4 nodes x 4 cols
  {
    int rowg = tid >> 4, colg = tid & 15;
    int rm = rowg * 4, cn = colg * 4;
    float acc[4][4];
#pragma unroll
    for (int i = 0; i < 4; ++i)
#pragma unroll
      for (int j = 0; j < 4; ++j) acc[i][j] = 0.f;
    for (int k0 = 0; k0 < 128; k0 += 4) {
      float av[4][4], bv[4][4];
#pragma unroll
      for (int i = 0; i < 4; ++i) {
        float4 a = *(const float4*)&sh1[rm + i][k0];
        av[i][0] = a.x; av[i][1] = a.y; av[i][2] = a.z; av[i][3] = a.w;
      }
#pragma unroll
      for (int kk = 0; kk < 4; ++kk) {
        float4 b = *(const float4*)&sW1[k0 + kk][cn];
        bv[kk][0] = b.x; bv[kk][1] = b.y; bv[kk][2] = b.z; bv[kk][3] = b.w;
      }
#pragma unroll
      for (int i = 0; i < 4; ++i)
#pragma unroll
        for (int j = 0; j < 4; ++j)
#pragma unroll
          for (int kk = 0; kk < 4; ++kk) acc[i][j] += av[i][kk] * bv[kk][j];
    }
    float4 bb = *(const float4*)(b1 + cn);
    float bbv[4] = {bb.x, bb.y, bb.z, bb.w};
#pragma unroll
    for (int i = 0; i < 4; ++i)
#pragma unroll
      for (int j = 0; j < 4; ++j)
        sh2[rm + i][cn + j] = fmaxf(acc[i][j] + bbv[j], 0.f);
  }
  __syncthreads();

  // layer C: 64 nodes x 3 outputs on 192 threads
  if (tid < 192) {
    int r = tid / 3, c = tid % 3;
    float s = b2[c];
#pragma unroll 4
    for (int k = 0; k < 64; ++k) s += sh2[r][k] * sW2[k * 3 + c];
    h3[(size_t)(n0 + r) * 3 + c] = s;
  }
}

// ---------------------------------------------------------------------------
// cdist: out[i,j] = ||h3_i - h3_j||_2 via direct differences (exact-0 diagonal).
__global__ __launch_bounds__(256) void cdist_kernel(const float* __restrict__ h3,
                                                    float* __restrict__ out) {
  int i = blockIdx.y;
  int j0 = blockIdx.x * 1024 + threadIdx.x * 4;
  float x0 = h3[(size_t)i * 3 + 0];
  float x1 = h3[(size_t)i * 3 + 1];
  float x2 = h3[(size_t)i * 3 + 2];
  const float* p = h3 + (size_t)j0 * 3;
  float4 q0 = ((const float4*)p)[0];
  float4 q1 = ((const float4*)p)[1];
  float4 q2 = ((const float4*)p)[2];
  auto dist = [&](float a, float b, float c) {
    float dx = x0 - a, dy = x1 - b, dz = x2 - c;
    return sqrtf(dx * dx + dy * dy + dz * dz);
  };
  float4 o;
  o.x = dist(q0.x, q0.y, q0.z);
  o.y = dist(q0.w, q1.x, q1.y);
  o.z = dist(q1.z, q1.w, q2.x);
  o.w = dist(q2.y, q2.z, q2.w);
  *(float4*)(out + (size_t)i * N_NODES + j0) = o;
}

// ---------------------------------------------------------------------------
extern "C" void kernel_launch(void* const* d_in, const int* in_sizes, int n_in,
                              void* d_out, int out_size, void* d_ws, size_t ws_size,
                              hipStream_t stream) {
  const float* x       = (const float*)d_in[0];
  const int*   ei      = (const int*)d_in[1];
  const float* W       = (const float*)d_in[2];
  const float* att_src = (const float*)d_in[3];
  const float* att_dst = (const float*)d_in[4];
  const float* bias    = (const float*)d_in[5];
  const float* Wa      = (const float*)d_in[6];
  const float* ba      = (const float*)d_in[7];
  const float* W1      = (const float*)d_in[8];
  const float* b1      = (const float*)d_in[9];
  const float* W2      = (const float*)d_in[10];
  const float* b2      = (const float*)d_in[11];
  float* out = (float*)d_out;

  // workspace layout (floats then ints, all 16B aligned)
  float* xh   = (float*)d_ws;
  float* hagg = xh + (size_t)N_NODES * DCAT;        // +16777216
  float* asrc = hagg + (size_t)N_NODES * DCAT;      // +16777216
  float* adst = asrc + N_NODES * 2;                 // +32768
  float* h3   = adst + N_NODES * 2;                 // +32768
  float* h1   = h3 + (size_t)N_NODES * 3;           // +49152
  int* rowptr = (int*)(h1 + (size_t)N_NODES * 128); // +2097152
  int* cnt    = rowptr + 16388;
  int* cursor = cnt + N_NODES;
  int* flag   = cursor + N_NODES;
  int* esrc   = flag + 4;

  hipMemsetAsync(cnt, 0, (size_t)(N_NODES + N_NODES + 4) * sizeof(int), stream);

  detect_kernel<<<1, 256, 0, stream>>>(ei, flag);
  count_kernel<<<(ET + 255) / 256, 256, 0, stream>>>(ei, flag, cnt);
  scan_kernel<<<1, 1024, 0, stream>>>(cnt, rowptr);
  scatter_kernel<<<(ET + 255) / 256, 256, 0, stream>>>(ei, flag, rowptr, cursor, esrc);

  gemm1_kernel<<<dim3(DCAT / 128, N_NODES / 128), 256, 0, stream>>>(x, W, xh);
  avec_kernel<<<N_NODES * 2 / 4, 256, 0, stream>>>(xh, att_src, att_dst, asrc, adst);
  agg_kernel<<<N_NODES, 256, 0, stream>>>(xh, asrc, adst, rowptr, esrc, bias, hagg);
  mlpA_kernel<<<N_NODES / 32, 256, 0, stream>>>(hagg, Wa, ba, h1);
  mlpBC_kernel<<<N_NODES / 64, 256, 0, stream>>>(h1, W1, b1, W2, b2, h3);
  cdist_kernel<<<dim3(N_NODES / 1024, N_NODES), 256, 0, stream>>>(h3, out);
}